// Round 12
// baseline (513.037 us; speedup 1.0000x reference)
//
#include <hip/hip_runtime.h>
#include <stdint.h>

typedef unsigned short u16;
typedef __attribute__((ext_vector_type(4))) float f32x4;
typedef __attribute__((ext_vector_type(8))) short bf16x8;
typedef bf16x8 bf16x8a __attribute__((may_alias));
typedef uint32_t u32a __attribute__((may_alias));

#define HID 1024
#define MLPD 4096
#define TEMB 1024
#define ADA_N 6144
#define SEQ 1024
#define BATCH 8
#define KCH 32          // ada split-K chunks
#define KCHLEN (TEMB / KCH)

// ---------- helpers ----------
__device__ __forceinline__ u16 f2bf_bits(float f) {
  uint32_t u = __float_as_uint(f);
  uint32_t r = (u + 0x7FFFu + ((u >> 16) & 1u)) >> 16;
  return (u16)r;
}

__device__ __forceinline__ uint32_t cvt_pk_bf16(float lo, float hi) {
  uint32_t r;
  asm("v_cvt_pk_bf16_f32 %0, %1, %2" : "=v"(r) : "v"(lo), "v"(hi));
  return r;
}

__device__ __forceinline__ float exp2_hw(float x) {
#if __has_builtin(__builtin_amdgcn_exp2f)
  return __builtin_amdgcn_exp2f(x);
#else
  return exp2f(x);
#endif
}

__device__ __forceinline__ void async_copy16(void* lds_dst, const void* g_src) {
  __builtin_amdgcn_global_load_lds(
      (const __attribute__((address_space(1))) void*)(uintptr_t)g_src,
      (__attribute__((address_space(3))) void*)(uint32_t)(uintptr_t)lds_dst,
      16, 0, 0);
}

__device__ __forceinline__ float gelu_tanh(float v) {
  float u = 0.7978845608028654f * (v + 0.044715f * v * v * v);
  float e = __expf(2.f * u);
  return v * e / (e + 1.f);   // = 0.5*v*(1+tanh(u))
}

// ---------- weight transpose fp32(KxN) -> bf16(NxK) ----------
__global__ __launch_bounds__(256) void transpose_bf16(const float* __restrict__ W,
                                                      u16* __restrict__ Wt, int K, int N) {
  __shared__ float tile[32][33];
  int n0 = blockIdx.x * 32, k0 = blockIdx.y * 32;
  int tx = threadIdx.x & 31, ty = threadIdx.x >> 5;   // 32 x 8
#pragma unroll
  for (int i = 0; i < 4; i++)
    tile[ty + i * 8][tx] = W[(size_t)(k0 + ty + i * 8) * N + n0 + tx];
  __syncthreads();
#pragma unroll
  for (int i = 0; i < 4; i++)
    Wt[(size_t)(n0 + ty + i * 8) * K + k0 + tx] = f2bf_bits(tile[tx][ty + i * 8]);
}

// ---------- ada split-K ----------
__global__ __launch_bounds__(256) void ada_part(const float* __restrict__ c,
                                                const float* __restrict__ W,
                                                float* __restrict__ part) {
  __shared__ float sc[BATCH * KCHLEN];
  int t = threadIdx.x;
  int col = blockIdx.x * 256 + t;
  int kc = blockIdx.y;
  int k0 = kc * KCHLEN;
  for (int i = t; i < BATCH * KCHLEN; i += 256) {
    int b = i >> 5, kk = i & (KCHLEN - 1);
    float v = c[b * TEMB + k0 + kk];
    sc[i] = v / (1.f + __expf(-v));
  }
  __syncthreads();
  float acc[BATCH] = {};
  for (int kk = 0; kk < KCHLEN; kk++) {
    float w = W[(size_t)(k0 + kk) * ADA_N + col];
#pragma unroll
    for (int b = 0; b < BATCH; b++) acc[b] += sc[b * KCHLEN + kk] * w;
  }
#pragma unroll
  for (int b = 0; b < BATCH; b++)
    part[((size_t)kc * BATCH + b) * ADA_N + col] = acc[b];
}

__global__ __launch_bounds__(256) void ada_reduce(const float* __restrict__ part,
                                                  const float* __restrict__ bias,
                                                  float* __restrict__ out) {
  int i = blockIdx.x * 256 + threadIdx.x;   // over 8*6144
  int col = i % ADA_N, b = i / ADA_N;
  float s = bias[col];
#pragma unroll
  for (int kc = 0; kc < KCH; kc++)
    s += part[((size_t)kc * BATCH + b) * ADA_N + col];
  out[(size_t)b * ADA_N + col] = s;
}

// ---------- fused LayerNorm + modulate -> bf16 ----------
__global__ __launch_bounds__(256) void ln_mod(const float* __restrict__ x,
                                              const float* __restrict__ ada,
                                              int shift_off, int scale_off,
                                              u16* __restrict__ h) {
  int row = blockIdx.x;        // 0..8191
  int bb = row >> 10;
  int t = threadIdx.x;
  const float4 v = ((const float4*)(x + (size_t)row * HID))[t];
  float s = v.x + v.y + v.z + v.w;
  float sq = v.x * v.x + v.y * v.y + v.z * v.z + v.w * v.w;
#pragma unroll
  for (int off = 32; off >= 1; off >>= 1) {
    s += __shfl_xor(s, off);
    sq += __shfl_xor(sq, off);
  }
  __shared__ float red[8];
  int wid = t >> 6;
  if ((t & 63) == 0) { red[wid] = s; red[4 + wid] = sq; }
  __syncthreads();
  s = red[0] + red[1] + red[2] + red[3];
  sq = red[4] + red[5] + red[6] + red[7];
  float mu = s * (1.0f / HID);
  float rs = rsqrtf(sq * (1.0f / HID) - mu * mu + 1e-6f);
  const float4 sc = ((const float4*)(ada + (size_t)bb * ADA_N + scale_off))[t];
  const float4 sh = ((const float4*)(ada + (size_t)bb * ADA_N + shift_off))[t];
  ushort4 o;
  o.x = f2bf_bits((v.x - mu) * rs * (1.f + sc.x) + sh.x);
  o.y = f2bf_bits((v.y - mu) * rs * (1.f + sc.y) + sh.y);
  o.z = f2bf_bits((v.z - mu) * rs * (1.f + sc.z) + sh.z);
  o.w = f2bf_bits((v.w - mu) * rs * (1.f + sc.w) + sh.w);
  ((ushort4*)(h + (size_t)row * HID))[t] = o;
}

// ---------- 8-phase 256xBN bf16 GEMM (round-6 config: session-best 404.8 us) ----------
// C(M x N) = A(M x K) * Bt(N x K)^T + bias. 512 thr / 8 waves (2M x 4N), BK=64.
// LDS tiles [rows][64] u16; chunk swizzle c16 ^= row&7 on BOTH the
// global_load_lds source and the ds_read (rule 21).
// EPI: 0 = bf16 out, 1 = gelu -> bf16 out, 2 = f32 out = resid + gate*(acc+bias)

template <int NLOAD>
__device__ __forceinline__ void stage_tile(u16* dst, const u16* gsrc, int K, int koff, int t) {
#pragma unroll
  for (int i = 0; i < NLOAD; ++i) {
    int slot = i * 512 + t;
    int row = slot >> 3, cp = slot & 7;
    const u16* src = gsrc + (size_t)row * K + koff + ((cp ^ (row & 7)) << 3);
    async_copy16(dst + slot * 8, src);
  }
}

#define LDSRD(buf, row, kk) \
  (*(const bf16x8a*)&(buf)[(row) * 64 + ((((kk) * 4 + l4) ^ ((row) & 7)) << 3)])

template <int EPI, int BN>
__global__ __launch_bounds__(512, 2) void gemm8(const u16* __restrict__ A,
                                                const u16* __restrict__ Bt,
                                                const float* __restrict__ bias,
                                                void* __restrict__ Cout,
                                                const float* __restrict__ resid,
                                                const float* __restrict__ gate,
                                                int N, int K) {
  constexpr int NR = BN / 64;       // 16x16 fragments per wave in N (4 or 2)
  constexpr int BLOADS = BN / 64;   // B stage loads per thread (4 or 2)
  constexpr int TOT = 4 + BLOADS;   // loads per thread per K-tile
  __shared__ u16 As[2][256 * 64];
  __shared__ u16 Bs[2][BN * 64];

  int t = threadIdx.x;
  int lane = t & 63, wid = t >> 6;
  int l15 = lane & 15, l4 = lane >> 4;
  int wr = wid >> 2, wc = wid & 3;            // 2 x 4 waves
  // XCD m-banding: 4 m-tiles per XCD (A-band <= 2 MB, L2-resident)
  int lid = blockIdx.x;
  int xcd = lid & 7, win = lid >> 3;
  int m0 = (xcd * 4 + (win & 3)) * 256;
  int n0 = (win >> 2) * BN;

  const u16* Abase = A + (size_t)m0 * K;
  const u16* Bbase = Bt + (size_t)n0 * K;
  f32x4 acc[8][NR] = {};

  u16 *cA = As[0], *cB = Bs[0], *nA = As[1], *nB = Bs[1];
  int nt = K / 64;
  // prologue: stage tiles 0 and 1; wait tile 0 (tile 1 stays in flight)
  stage_tile<4>(cA, Abase, K, 0, t);
  stage_tile<BLOADS>(cB, Bbase, K, 0, t);
  stage_tile<4>(nA, Abase, K, 64, t);
  stage_tile<BLOADS>(nB, Bbase, K, 64, t);
  if constexpr (TOT == 8) asm volatile("s_waitcnt vmcnt(8)" ::: "memory");
  else                    asm volatile("s_waitcnt vmcnt(6)" ::: "memory");
  __builtin_amdgcn_s_barrier();
  __builtin_amdgcn_sched_barrier(0);

  for (int ts = 0; ts < nt; ++ts) {
    bf16x8 bf[NR][2];
#pragma unroll
    for (int p = 0; p < 4; ++p) {
      if (p == 0) {
#pragma unroll
        for (int ni = 0; ni < NR; ++ni)
#pragma unroll
          for (int kk = 0; kk < 2; ++kk)
            bf[ni][kk] = LDSRD(cB, wc * (16 * NR) + ni * 16 + l15, kk);
      }
      bf16x8 af[2][2];
#pragma unroll
      for (int i = 0; i < 2; ++i)
#pragma unroll
        for (int kk = 0; kk < 2; ++kk)
          af[i][kk] = LDSRD(cA, wr * 128 + (p * 2 + i) * 16 + l15, kk);
      asm volatile("s_waitcnt lgkmcnt(0)" ::: "memory");
      __builtin_amdgcn_sched_barrier(0);
      __builtin_amdgcn_s_setprio(1);
#pragma unroll
      for (int i = 0; i < 2; ++i)
#pragma unroll
        for (int ni = 0; ni < NR; ++ni) {
          acc[p * 2 + i][ni] = __builtin_amdgcn_mfma_f32_16x16x32_bf16(af[i][0], bf[ni][0], acc[p * 2 + i][ni], 0, 0, 0);
          acc[p * 2 + i][ni] = __builtin_amdgcn_mfma_f32_16x16x32_bf16(af[i][1], bf[ni][1], acc[p * 2 + i][ni], 0, 0, 0);
        }
      __builtin_amdgcn_s_setprio(0);
      __builtin_amdgcn_sched_barrier(0);
      __builtin_amdgcn_s_barrier();   // phase boundary: all waves done reading this quadrant
      __builtin_amdgcn_sched_barrier(0);
    }
    // iteration end: cur fully read by all waves (phase-3 barrier passed).
    if (ts + 2 < nt) {
      stage_tile<4>(cA, Abase, K, (ts + 2) * 64, t);        // overwrite cur with tile t+2
      stage_tile<BLOADS>(cB, Bbase, K, (ts + 2) * 64, t);
      if constexpr (TOT == 8) asm volatile("s_waitcnt vmcnt(8)" ::: "memory");
      else                    asm volatile("s_waitcnt vmcnt(6)" ::: "memory");
    } else if (ts + 1 < nt) {
      asm volatile("s_waitcnt vmcnt(0)" ::: "memory");
    }
    __builtin_amdgcn_s_barrier();
    __builtin_amdgcn_sched_barrier(0);
    u16* tp;
    tp = cA; cA = nA; nA = tp;
    tp = cB; cB = nB; nB = tp;
  }

  int brow = m0 + wr * 128, bcol = n0 + wc * (16 * NR);
  int bb = m0 >> 10;  // 256-row tile lies within one batch
#pragma unroll
  for (int ni = 0; ni < NR; ++ni) {
    int col = bcol + ni * 16 + l15;
    float bv = bias[col];
    float gv = (EPI == 2) ? gate[(size_t)bb * ADA_N + col] : 0.f;
#pragma unroll
    for (int mi = 0; mi < 8; ++mi) {
#pragma unroll
      for (int r = 0; r < 4; ++r) {
        int row = brow + mi * 16 + l4 * 4 + r;
        float v = acc[mi][ni][r] + bv;
        if (EPI == 0) {
          ((u16*)Cout)[(size_t)row * N + col] = f2bf_bits(v);
        } else if (EPI == 1) {
          ((u16*)Cout)[(size_t)row * N + col] = f2bf_bits(gelu_tanh(v));
        } else {
          ((float*)Cout)[(size_t)row * N + col] =
              resid[(size_t)row * N + col] + gv * v;
        }
      }
    }
  }
}

// ---------- flash attention, swapped-operand structure ----------
// (256,4): VGPR=64 measured -> 4 blocks/CU co-resident (was 3); grid = 1024 = 4/CU.
__global__ __launch_bounds__(256, 4) void attn_kernel(const u16* __restrict__ qkv,
                                                      u16* __restrict__ O) {
  const int KSTR = 72, VSTR = 72, PSTR = 72;  // u16 strides, 16B-aligned rows
  __shared__ u16 Ks[64 * 72];       // K chunk rows [kv][d]
  __shared__ u16 Vt[64 * 72];       // V chunk transposed [d][kv]
  __shared__ u16 Plds[4 * 16 * 72]; // per-wave P rows [q][kv]
  int t = threadIdx.x, lane = t & 63, wid = t >> 6;
  int l15 = lane & 15, l4 = lane >> 4;
  // T1: all 8 q-tiles of one (b,h) + 16 consecutive bh land on one XCD (KV L2 reuse)
  int work = ((blockIdx.x & 7) << 7) + (blockIdx.x >> 3);   // nwg = 1024
  int bh = work >> 3, qt8 = work & 7;
  int b = bh >> 4, h = bh & 15;
  int bRow = b * SEQ;
  int hOff = h * 64;
  int q0 = qt8 * 128 + wid * 32;

  // Q fragments (B-operand): lane l15 = q-row, k = d = l4*8+e
  bf16x8 qr[2][2];
#pragma unroll
  for (int qt = 0; qt < 2; qt++) {
    const u16* qbase = qkv + (size_t)(bRow + q0 + qt * 16 + l15) * 3072 + hOff;
    qr[qt][0] = *(const bf16x8a*)(qbase + l4 * 8);
    qr[qt][1] = *(const bf16x8a*)(qbase + 32 + l4 * 8);
  }

  const float csc = 0.125f * 1.4426950408889634f;  // scale * log2(e)
  float mrow[2] = {-1e30f, -1e30f};
  float lsum[2] = {0.f, 0.f};
  f32x4 o[2][4] = {};   // O^T: [qt][dt], lane: q=l15 (col), d=dt*16+l4*4+r (row)
  u16* pw = Plds + wid * 16 * PSTR;

  for (int cc = 0; cc < 16; cc++) {
    int kv0 = cc * 64;
    __syncthreads();
    // stage K rows (row-major, padded)
#pragma unroll
    for (int i = 0; i < 2; i++) {
      int idx = i * 256 + t;
      int row = idx >> 3, ch = idx & 7;
      bf16x8 kk = *(const bf16x8a*)(qkv + (size_t)(bRow + kv0 + row) * 3072 + 1024 + hOff + ch * 8);
      *(bf16x8a*)&Ks[row * KSTR + ch * 8] = kk;
    }
    // stage V transposed (dc-staggered scalar writes)
#pragma unroll
    for (int i = 0; i < 2; i++) {
      int idx = i * 256 + t;
      int kv = idx >> 3, dc = idx & 7;
      bf16x8 vv = *(const bf16x8a*)(qkv + (size_t)(bRow + kv0 + kv) * 3072 + 2048 + hOff + dc * 8);
#pragma unroll
      for (int j = 0; j < 8; j++) {
        int jj = (j + dc) & 7;
        Vt[(dc * 8 + jj) * VSTR + kv] = ((const u16*)&vv)[jj];
      }
    }
    __syncthreads();

    // K A-fragments: lane l15 = kv-row, k = d
    bf16x8 ak[4][2];
#pragma unroll
    for (int kt = 0; kt < 4; kt++) {
      ak[kt][0] = *(const bf16x8a*)&Ks[(kt * 16 + l15) * KSTR + l4 * 8];
      ak[kt][1] = *(const bf16x8a*)&Ks[(kt * 16 + l15) * KSTR + 32 + l4 * 8];
    }
    // S^T = K . Q^T (raw, unscaled)
    f32x4 st[2][4];
#pragma unroll
    for (int qt = 0; qt < 2; qt++)
#pragma unroll
      for (int kt = 0; kt < 4; kt++) {
        f32x4 z = {0.f, 0.f, 0.f, 0.f};
        z = __builtin_amdgcn_mfma_f32_16x16x32_bf16(ak[kt][0], qr[qt][0], z, 0, 0, 0);
        z = __builtin_amdgcn_mfma_f32_16x16x32_bf16(ak[kt][1], qr[qt][1], z, 0, 0, 0);
        st[qt][kt] = z;
      }
    // V^T A-fragments: lane l15 = d-row, k = kv
    bf16x8 av[4][2];
#pragma unroll
    for (int dt = 0; dt < 4; dt++) {
      av[dt][0] = *(const bf16x8a*)&Vt[(dt * 16 + l15) * VSTR + l4 * 8];
      av[dt][1] = *(const bf16x8a*)&Vt[(dt * 16 + l15) * VSTR + 32 + l4 * 8];
    }

#pragma unroll
    for (int qt = 0; qt < 2; qt++) {
      float mx = st[qt][0][0];
#pragma unroll
      for (int kt = 0; kt < 4; kt++)
#pragma unroll
        for (int r = 0; r < 4; r++) mx = fmaxf(mx, st[qt][kt][r]);
      mx = fmaxf(mx, __shfl_xor(mx, 16));
      mx = fmaxf(mx, __shfl_xor(mx, 32));
      float mn = fmaxf(mrow[qt], mx * csc);
      float al = exp2_hw(mrow[qt] - mn);
      mrow[qt] = mn;
      float rs = 0.f;
#pragma unroll
      for (int kt = 0; kt < 4; kt++)
#pragma unroll
        for (int r = 0; r < 4; r++) {
          float p = exp2_hw(__builtin_fmaf(st[qt][kt][r], csc, -mn));
          st[qt][kt][r] = p;
          rs += p;
        }
      rs += __shfl_xor(rs, 16);
      rs += __shfl_xor(rs, 32);
      lsum[qt] = lsum[qt] * al + rs;
#pragma unroll
      for (int dt = 0; dt < 4; dt++) o[qt][dt] *= al;
      // P -> LDS row q=l15 via packed bf16 writes (may_alias: keeps TBAA ordering)
#pragma unroll
      for (int kt = 0; kt < 4; kt++) {
#pragma unroll
        for (int hh = 0; hh < 2; hh++) {
          uint32_t pk = cvt_pk_bf16(st[qt][kt][2 * hh], st[qt][kt][2 * hh + 1]);
          *(u32a*)&pw[l15 * PSTR + kt * 16 + l4 * 4 + 2 * hh] = pk;
        }
      }
      // hard fence: P writes must complete before P fragment reads (rule 18 pattern)
      asm volatile("s_waitcnt lgkmcnt(0)" ::: "memory");
      __builtin_amdgcn_sched_barrier(0);
      // P B-fragments: lane l15 = q-row, k = kv
      bf16x8 bp0 = *(const bf16x8a*)&pw[l15 * PSTR + l4 * 8];
      bf16x8 bp1 = *(const bf16x8a*)&pw[l15 * PSTR + 32 + l4 * 8];
#pragma unroll
      for (int dt = 0; dt < 4; dt++) {
        o[qt][dt] = __builtin_amdgcn_mfma_f32_16x16x32_bf16(av[dt][0], bp0, o[qt][dt], 0, 0, 0);
        o[qt][dt] = __builtin_amdgcn_mfma_f32_16x16x32_bf16(av[dt][1], bp1, o[qt][dt], 0, 0, 0);
      }
      // P reads of this qt must finish before next qt overwrites pw
      asm volatile("s_waitcnt lgkmcnt(0)" ::: "memory");
      __builtin_amdgcn_sched_barrier(0);
    }
  }
  // epilogue: O^T lane holds q=l15, d = dt*16 + l4*4 + {0..3}
#pragma unroll
  for (int qt = 0; qt < 2; qt++) {
    float inv = 1.f / lsum[qt];
    u16* orow = O + (size_t)(bRow + q0 + qt * 16 + l15) * HID + hOff;
#pragma unroll
    for (int dt = 0; dt < 4; dt++) {
      uint2 w;
      w.x = cvt_pk_bf16(o[qt][dt][0] * inv, o[qt][dt][1] * inv);
      w.y = cvt_pk_bf16(o[qt][dt][2] * inv, o[qt][dt][3] * inv);
      *(uint2*)(orow + dt * 16 + l4 * 4) = w;
    }
  }
}

// ---------- launch ----------
extern "C" void kernel_launch(void* const* d_in, const int* in_sizes, int n_in,
                              void* d_out, int out_size, void* d_ws, size_t ws_size,
                              hipStream_t stream) {
  const float* x      = (const float*)d_in[0];
  const float* c      = (const float*)d_in[1];
  const float* W_qkv  = (const float*)d_in[2];
  const float* b_qkv  = (const float*)d_in[3];
  const float* W_proj = (const float*)d_in[4];
  const float* b_proj = (const float*)d_in[5];
  const float* W_fc1  = (const float*)d_in[6];
  const float* b_fc1  = (const float*)d_in[7];
  const float* W_fc2  = (const float*)d_in[8];
  const float* b_fc2  = (const float*)d_in[9];
  const float* W_ada  = (const float*)d_in[10];
  const float* b_ada  = (const float*)d_in[11];
  float* out = (float*)d_out;
  char* ws = (char*)d_ws;

  // workspace layout (bytes)
  float* ada  = (float*)(ws + 0);            // 8x6144 f32
  u16* WtQKV  = (u16*)(ws + 196608);         // 3072x1024 bf16
  u16* WtP    = (u16*)(ws + 6488064);        // 1024x1024 bf16
  u16* WtF1   = (u16*)(ws + 8585216);        // 4096x1024 bf16
  u16* WtF2   = (u16*)(ws + 16973824);       // 1024x4096 bf16
  u16* hbuf   = (u16*)(ws + 25362432);       // 8192x1024 bf16 (h / attnO / h2)
  u16* big    = (u16*)(ws + 42139648);       // 8192x4096 bf16 max (qkv / gelu-out)
  // ada split-K partials live inside `big` (only used before qkv GEMM writes it)
  float* apart = (float*)(ws + 42139648);    // 32x8x6144 f32 = 6.29 MB

  transpose_bf16<<<dim3(3072 / 32, 1024 / 32), 256, 0, stream>>>(W_qkv, WtQKV, 1024, 3072);
  transpose_bf16<<<dim3(1024 / 32, 1024 / 32), 256, 0, stream>>>(W_proj, WtP, 1024, 1024);
  transpose_bf16<<<dim3(4096 / 32, 1024 / 32), 256, 0, stream>>>(W_fc1, WtF1, 1024, 4096);
  transpose_bf16<<<dim3(1024 / 32, 4096 / 32), 256, 0, stream>>>(W_fc2, WtF2, 4096, 1024);
  ada_part<<<dim3(ADA_N / 256, KCH), 256, 0, stream>>>(c, W_ada, apart);
  ada_reduce<<<(BATCH * ADA_N) / 256, 256, 0, stream>>>(apart, b_ada, ada);
  ln_mod<<<8192, 256, 0, stream>>>(x, ada, 0, 1024, hbuf);
  // qkv: BN=128 -> 32*24 = 768 blocks (3 full CU rounds)
  gemm8<0, 128><<<768, 512, 0, stream>>>(hbuf, WtQKV, b_qkv, big, nullptr, nullptr, 3072, 1024);
  attn_kernel<<<1024, 256, 0, stream>>>(big, hbuf);
  // proj: BN=128 -> 256 blocks (1 round)
  gemm8<2, 128><<<256, 512, 0, stream>>>(hbuf, WtP, b_proj, out, x, ada + 2048, 1024, 1024);
  ln_mod<<<8192, 256, 0, stream>>>(out, ada, 3072, 4096, hbuf);
  // fc1: BN=256 -> 32*16 = 512 blocks (2 rounds)
  gemm8<1, 256><<<512, 512, 0, stream>>>(hbuf, WtF1, b_fc1, big, nullptr, nullptr, 4096, 1024);
  // fc2: BN=128, K=4096 -> 256 blocks (1 round)
  gemm8<2, 128><<<256, 512, 0, stream>>>(big, WtF2, b_fc2, out, out, ada + 5120, 1024, 4096);
}

// Round 13
// 405.306 us; speedup vs baseline: 1.2658x; 1.2658x over previous
//
#include <hip/hip_runtime.h>
#include <stdint.h>

typedef unsigned short u16;
typedef __attribute__((ext_vector_type(4))) float f32x4;
typedef __attribute__((ext_vector_type(8))) short bf16x8;
typedef bf16x8 bf16x8a __attribute__((may_alias));
typedef uint32_t u32a __attribute__((may_alias));

#define HID 1024
#define MLPD 4096
#define TEMB 1024
#define ADA_N 6144
#define SEQ 1024
#define BATCH 8
#define KCH 32          // ada split-K chunks
#define KCHLEN (TEMB / KCH)

// ---------- helpers ----------
__device__ __forceinline__ u16 f2bf_bits(float f) {
  uint32_t u = __float_as_uint(f);
  uint32_t r = (u + 0x7FFFu + ((u >> 16) & 1u)) >> 16;
  return (u16)r;
}

__device__ __forceinline__ uint32_t cvt_pk_bf16(float lo, float hi) {
  uint32_t r;
  asm("v_cvt_pk_bf16_f32 %0, %1, %2" : "=v"(r) : "v"(lo), "v"(hi));
  return r;
}

__device__ __forceinline__ float exp2_hw(float x) {
#if __has_builtin(__builtin_amdgcn_exp2f)
  return __builtin_amdgcn_exp2f(x);
#else
  return exp2f(x);
#endif
}

__device__ __forceinline__ void async_copy16(void* lds_dst, const void* g_src) {
  __builtin_amdgcn_global_load_lds(
      (const __attribute__((address_space(1))) void*)(uintptr_t)g_src,
      (__attribute__((address_space(3))) void*)(uint32_t)(uintptr_t)lds_dst,
      16, 0, 0);
}

__device__ __forceinline__ float gelu_tanh(float v) {
  float u = 0.7978845608028654f * (v + 0.044715f * v * v * v);
  float e = __expf(2.f * u);
  return v * e / (e + 1.f);   // = 0.5*v*(1+tanh(u))
}

// ---------- weight transpose fp32(KxN) -> bf16(NxK) ----------
__global__ __launch_bounds__(256) void transpose_bf16(const float* __restrict__ W,
                                                      u16* __restrict__ Wt, int K, int N) {
  __shared__ float tile[32][33];
  int n0 = blockIdx.x * 32, k0 = blockIdx.y * 32;
  int tx = threadIdx.x & 31, ty = threadIdx.x >> 5;   // 32 x 8
#pragma unroll
  for (int i = 0; i < 4; i++)
    tile[ty + i * 8][tx] = W[(size_t)(k0 + ty + i * 8) * N + n0 + tx];
  __syncthreads();
#pragma unroll
  for (int i = 0; i < 4; i++)
    Wt[(size_t)(n0 + ty + i * 8) * K + k0 + tx] = f2bf_bits(tile[tx][ty + i * 8]);
}

// ---------- ada split-K ----------
__global__ __launch_bounds__(256) void ada_part(const float* __restrict__ c,
                                                const float* __restrict__ W,
                                                float* __restrict__ part) {
  __shared__ float sc[BATCH * KCHLEN];
  int t = threadIdx.x;
  int col = blockIdx.x * 256 + t;
  int kc = blockIdx.y;
  int k0 = kc * KCHLEN;
  for (int i = t; i < BATCH * KCHLEN; i += 256) {
    int b = i >> 5, kk = i & (KCHLEN - 1);
    float v = c[b * TEMB + k0 + kk];
    sc[i] = v / (1.f + __expf(-v));
  }
  __syncthreads();
  float acc[BATCH] = {};
  for (int kk = 0; kk < KCHLEN; kk++) {
    float w = W[(size_t)(k0 + kk) * ADA_N + col];
#pragma unroll
    for (int b = 0; b < BATCH; b++) acc[b] += sc[b * KCHLEN + kk] * w;
  }
#pragma unroll
  for (int b = 0; b < BATCH; b++)
    part[((size_t)kc * BATCH + b) * ADA_N + col] = acc[b];
}

__global__ __launch_bounds__(256) void ada_reduce(const float* __restrict__ part,
                                                  const float* __restrict__ bias,
                                                  float* __restrict__ out) {
  int i = blockIdx.x * 256 + threadIdx.x;   // over 8*6144
  int col = i % ADA_N, b = i / ADA_N;
  float s = bias[col];
#pragma unroll
  for (int kc = 0; kc < KCH; kc++)
    s += part[((size_t)kc * BATCH + b) * ADA_N + col];
  out[(size_t)b * ADA_N + col] = s;
}

// ---------- fused LayerNorm + modulate -> bf16 ----------
__global__ __launch_bounds__(256) void ln_mod(const float* __restrict__ x,
                                              const float* __restrict__ ada,
                                              int shift_off, int scale_off,
                                              u16* __restrict__ h) {
  int row = blockIdx.x;        // 0..8191
  int bb = row >> 10;
  int t = threadIdx.x;
  const float4 v = ((const float4*)(x + (size_t)row * HID))[t];
  float s = v.x + v.y + v.z + v.w;
  float sq = v.x * v.x + v.y * v.y + v.z * v.z + v.w * v.w;
#pragma unroll
  for (int off = 32; off >= 1; off >>= 1) {
    s += __shfl_xor(s, off);
    sq += __shfl_xor(sq, off);
  }
  __shared__ float red[8];
  int wid = t >> 6;
  if ((t & 63) == 0) { red[wid] = s; red[4 + wid] = sq; }
  __syncthreads();
  s = red[0] + red[1] + red[2] + red[3];
  sq = red[4] + red[5] + red[6] + red[7];
  float mu = s * (1.0f / HID);
  float rs = rsqrtf(sq * (1.0f / HID) - mu * mu + 1e-6f);
  const float4 sc = ((const float4*)(ada + (size_t)bb * ADA_N + scale_off))[t];
  const float4 sh = ((const float4*)(ada + (size_t)bb * ADA_N + shift_off))[t];
  ushort4 o;
  o.x = f2bf_bits((v.x - mu) * rs * (1.f + sc.x) + sh.x);
  o.y = f2bf_bits((v.y - mu) * rs * (1.f + sc.y) + sh.y);
  o.z = f2bf_bits((v.z - mu) * rs * (1.f + sc.z) + sh.z);
  o.w = f2bf_bits((v.w - mu) * rs * (1.f + sc.w) + sh.w);
  ((ushort4*)(h + (size_t)row * HID))[t] = o;
}

// ---------- 8-phase 256xBN bf16 GEMM (round-6 config: session-best 404.8 us) ----------
// C(M x N) = A(M x K) * Bt(N x K)^T + bias. 512 thr / 8 waves (2M x 4N), BK=64.
// LDS tiles [rows][64] u16; chunk swizzle c16 ^= row&7 on BOTH the
// global_load_lds source and the ds_read (rule 21).
// EPI: 0 = bf16 out, 1 = gelu -> bf16 out, 2 = f32 out = resid + gate*(acc+bias)

template <int NLOAD>
__device__ __forceinline__ void stage_tile(u16* dst, const u16* gsrc, int K, int koff, int t) {
#pragma unroll
  for (int i = 0; i < NLOAD; ++i) {
    int slot = i * 512 + t;
    int row = slot >> 3, cp = slot & 7;
    const u16* src = gsrc + (size_t)row * K + koff + ((cp ^ (row & 7)) << 3);
    async_copy16(dst + slot * 8, src);
  }
}

#define LDSRD(buf, row, kk) \
  (*(const bf16x8a*)&(buf)[(row) * 64 + ((((kk) * 4 + l4) ^ ((row) & 7)) << 3)])

template <int EPI, int BN>
__global__ __launch_bounds__(512, 2) void gemm8(const u16* __restrict__ A,
                                                const u16* __restrict__ Bt,
                                                const float* __restrict__ bias,
                                                void* __restrict__ Cout,
                                                const float* __restrict__ resid,
                                                const float* __restrict__ gate,
                                                int N, int K) {
  constexpr int NR = BN / 64;       // 16x16 fragments per wave in N (4 or 2)
  constexpr int BLOADS = BN / 64;   // B stage loads per thread (4 or 2)
  constexpr int TOT = 4 + BLOADS;   // loads per thread per K-tile
  __shared__ u16 As[2][256 * 64];
  __shared__ u16 Bs[2][BN * 64];

  int t = threadIdx.x;
  int lane = t & 63, wid = t >> 6;
  int l15 = lane & 15, l4 = lane >> 4;
  int wr = wid >> 2, wc = wid & 3;            // 2 x 4 waves
  // XCD m-banding: 4 m-tiles per XCD (A-band <= 2 MB, L2-resident)
  int lid = blockIdx.x;
  int xcd = lid & 7, win = lid >> 3;
  int m0 = (xcd * 4 + (win & 3)) * 256;
  int n0 = (win >> 2) * BN;

  const u16* Abase = A + (size_t)m0 * K;
  const u16* Bbase = Bt + (size_t)n0 * K;
  f32x4 acc[8][NR] = {};

  u16 *cA = As[0], *cB = Bs[0], *nA = As[1], *nB = Bs[1];
  int nt = K / 64;
  // prologue: stage tiles 0 and 1; wait tile 0 (tile 1 stays in flight)
  stage_tile<4>(cA, Abase, K, 0, t);
  stage_tile<BLOADS>(cB, Bbase, K, 0, t);
  stage_tile<4>(nA, Abase, K, 64, t);
  stage_tile<BLOADS>(nB, Bbase, K, 64, t);
  if constexpr (TOT == 8) asm volatile("s_waitcnt vmcnt(8)" ::: "memory");
  else                    asm volatile("s_waitcnt vmcnt(6)" ::: "memory");
  __builtin_amdgcn_s_barrier();
  __builtin_amdgcn_sched_barrier(0);

  for (int ts = 0; ts < nt; ++ts) {
    bf16x8 bf[NR][2];
#pragma unroll
    for (int p = 0; p < 4; ++p) {
      if (p == 0) {
#pragma unroll
        for (int ni = 0; ni < NR; ++ni)
#pragma unroll
          for (int kk = 0; kk < 2; ++kk)
            bf[ni][kk] = LDSRD(cB, wc * (16 * NR) + ni * 16 + l15, kk);
      }
      bf16x8 af[2][2];
#pragma unroll
      for (int i = 0; i < 2; ++i)
#pragma unroll
        for (int kk = 0; kk < 2; ++kk)
          af[i][kk] = LDSRD(cA, wr * 128 + (p * 2 + i) * 16 + l15, kk);
      asm volatile("s_waitcnt lgkmcnt(0)" ::: "memory");
      __builtin_amdgcn_sched_barrier(0);
      __builtin_amdgcn_s_setprio(1);
#pragma unroll
      for (int i = 0; i < 2; ++i)
#pragma unroll
        for (int ni = 0; ni < NR; ++ni) {
          acc[p * 2 + i][ni] = __builtin_amdgcn_mfma_f32_16x16x32_bf16(af[i][0], bf[ni][0], acc[p * 2 + i][ni], 0, 0, 0);
          acc[p * 2 + i][ni] = __builtin_amdgcn_mfma_f32_16x16x32_bf16(af[i][1], bf[ni][1], acc[p * 2 + i][ni], 0, 0, 0);
        }
      __builtin_amdgcn_s_setprio(0);
      __builtin_amdgcn_sched_barrier(0);
      __builtin_amdgcn_s_barrier();   // phase boundary: all waves done reading this quadrant
      __builtin_amdgcn_sched_barrier(0);
    }
    // iteration end: cur fully read by all waves (phase-3 barrier passed).
    if (ts + 2 < nt) {
      stage_tile<4>(cA, Abase, K, (ts + 2) * 64, t);        // overwrite cur with tile t+2
      stage_tile<BLOADS>(cB, Bbase, K, (ts + 2) * 64, t);
      if constexpr (TOT == 8) asm volatile("s_waitcnt vmcnt(8)" ::: "memory");
      else                    asm volatile("s_waitcnt vmcnt(6)" ::: "memory");
    } else if (ts + 1 < nt) {
      asm volatile("s_waitcnt vmcnt(0)" ::: "memory");
    }
    __builtin_amdgcn_s_barrier();
    __builtin_amdgcn_sched_barrier(0);
    u16* tp;
    tp = cA; cA = nA; nA = tp;
    tp = cB; cB = nB; nB = tp;
  }

  int brow = m0 + wr * 128, bcol = n0 + wc * (16 * NR);
  int bb = m0 >> 10;  // 256-row tile lies within one batch
#pragma unroll
  for (int ni = 0; ni < NR; ++ni) {
    int col = bcol + ni * 16 + l15;
    float bv = bias[col];
    float gv = (EPI == 2) ? gate[(size_t)bb * ADA_N + col] : 0.f;
#pragma unroll
    for (int mi = 0; mi < 8; ++mi) {
#pragma unroll
      for (int r = 0; r < 4; ++r) {
        int row = brow + mi * 16 + l4 * 4 + r;
        float v = acc[mi][ni][r] + bv;
        if (EPI == 0) {
          ((u16*)Cout)[(size_t)row * N + col] = f2bf_bits(v);
        } else if (EPI == 1) {
          ((u16*)Cout)[(size_t)row * N + col] = f2bf_bits(gelu_tanh(v));
        } else {
          ((float*)Cout)[(size_t)row * N + col] =
              resid[(size_t)row * N + col] + gv * v;
        }
      }
    }
  }
}

// ---------- flash attention, swapped-operand structure ----------
// (256,3): 3 blocks/CU -> ~96 of 128 blocks/XCD resident, sliding ~12-bh KV
// window (~3 MB) fits the 4 MB per-XCD L2. (256,4) thrashes it (r12: 445 MB
// fetch, attn 93 -> 196 us). Do not raise occupancy here.
__global__ __launch_bounds__(256, 3) void attn_kernel(const u16* __restrict__ qkv,
                                                      u16* __restrict__ O) {
  const int KSTR = 72, VSTR = 72, PSTR = 72;  // u16 strides, 16B-aligned rows
  __shared__ u16 Ks[64 * 72];       // K chunk rows [kv][d]
  __shared__ u16 Vt[64 * 72];       // V chunk transposed [d][kv]
  __shared__ u16 Plds[4 * 16 * 72]; // per-wave P rows [q][kv]
  int t = threadIdx.x, lane = t & 63, wid = t >> 6;
  int l15 = lane & 15, l4 = lane >> 4;
  // T1: all 8 q-tiles of one (b,h) + 16 consecutive bh land on one XCD (KV L2 reuse)
  int work = ((blockIdx.x & 7) << 7) + (blockIdx.x >> 3);   // nwg = 1024
  int bh = work >> 3, qt8 = work & 7;
  int b = bh >> 4, h = bh & 15;
  int bRow = b * SEQ;
  int hOff = h * 64;
  int q0 = qt8 * 128 + wid * 32;

  // Q fragments (B-operand): lane l15 = q-row, k = d = l4*8+e
  bf16x8 qr[2][2];
#pragma unroll
  for (int qt = 0; qt < 2; qt++) {
    const u16* qbase = qkv + (size_t)(bRow + q0 + qt * 16 + l15) * 3072 + hOff;
    qr[qt][0] = *(const bf16x8a*)(qbase + l4 * 8);
    qr[qt][1] = *(const bf16x8a*)(qbase + 32 + l4 * 8);
  }

  const float csc = 0.125f * 1.4426950408889634f;  // scale * log2(e)
  float mrow[2] = {-1e30f, -1e30f};
  float lsum[2] = {0.f, 0.f};
  f32x4 o[2][4] = {};   // O^T: [qt][dt], lane: q=l15 (col), d=dt*16+l4*4+r (row)
  u16* pw = Plds + wid * 16 * PSTR;

  for (int cc = 0; cc < 16; cc++) {
    int kv0 = cc * 64;
    __syncthreads();
    // stage K rows (row-major, padded)
#pragma unroll
    for (int i = 0; i < 2; i++) {
      int idx = i * 256 + t;
      int row = idx >> 3, ch = idx & 7;
      bf16x8 kk = *(const bf16x8a*)(qkv + (size_t)(bRow + kv0 + row) * 3072 + 1024 + hOff + ch * 8);
      *(bf16x8a*)&Ks[row * KSTR + ch * 8] = kk;
    }
    // stage V transposed (dc-staggered scalar writes)
#pragma unroll
    for (int i = 0; i < 2; i++) {
      int idx = i * 256 + t;
      int kv = idx >> 3, dc = idx & 7;
      bf16x8 vv = *(const bf16x8a*)(qkv + (size_t)(bRow + kv0 + kv) * 3072 + 2048 + hOff + dc * 8);
#pragma unroll
      for (int j = 0; j < 8; j++) {
        int jj = (j + dc) & 7;
        Vt[(dc * 8 + jj) * VSTR + kv] = ((const u16*)&vv)[jj];
      }
    }
    __syncthreads();

    // K A-fragments: lane l15 = kv-row, k = d
    bf16x8 ak[4][2];
#pragma unroll
    for (int kt = 0; kt < 4; kt++) {
      ak[kt][0] = *(const bf16x8a*)&Ks[(kt * 16 + l15) * KSTR + l4 * 8];
      ak[kt][1] = *(const bf16x8a*)&Ks[(kt * 16 + l15) * KSTR + 32 + l4 * 8];
    }
    // S^T = K . Q^T (raw, unscaled)
    f32x4 st[2][4];
#pragma unroll
    for (int qt = 0; qt < 2; qt++)
#pragma unroll
      for (int kt = 0; kt < 4; kt++) {
        f32x4 z = {0.f, 0.f, 0.f, 0.f};
        z = __builtin_amdgcn_mfma_f32_16x16x32_bf16(ak[kt][0], qr[qt][0], z, 0, 0, 0);
        z = __builtin_amdgcn_mfma_f32_16x16x32_bf16(ak[kt][1], qr[qt][1], z, 0, 0, 0);
        st[qt][kt] = z;
      }
    // V^T A-fragments: lane l15 = d-row, k = kv
    bf16x8 av[4][2];
#pragma unroll
    for (int dt = 0; dt < 4; dt++) {
      av[dt][0] = *(const bf16x8a*)&Vt[(dt * 16 + l15) * VSTR + l4 * 8];
      av[dt][1] = *(const bf16x8a*)&Vt[(dt * 16 + l15) * VSTR + 32 + l4 * 8];
    }

#pragma unroll
    for (int qt = 0; qt < 2; qt++) {
      float mx = st[qt][0][0];
#pragma unroll
      for (int kt = 0; kt < 4; kt++)
#pragma unroll
        for (int r = 0; r < 4; r++) mx = fmaxf(mx, st[qt][kt][r]);
      mx = fmaxf(mx, __shfl_xor(mx, 16));
      mx = fmaxf(mx, __shfl_xor(mx, 32));
      float mn = fmaxf(mrow[qt], mx * csc);
      float al = exp2_hw(mrow[qt] - mn);
      mrow[qt] = mn;
      float rs = 0.f;
#pragma unroll
      for (int kt = 0; kt < 4; kt++)
#pragma unroll
        for (int r = 0; r < 4; r++) {
          float p = exp2_hw(__builtin_fmaf(st[qt][kt][r], csc, -mn));
          st[qt][kt][r] = p;
          rs += p;
        }
      rs += __shfl_xor(rs, 16);
      rs += __shfl_xor(rs, 32);
      lsum[qt] = lsum[qt] * al + rs;
#pragma unroll
      for (int dt = 0; dt < 4; dt++) o[qt][dt] *= al;
      // P -> LDS row q=l15 via packed bf16 writes (may_alias: keeps TBAA ordering)
#pragma unroll
      for (int kt = 0; kt < 4; kt++) {
#pragma unroll
        for (int hh = 0; hh < 2; hh++) {
          uint32_t pk = cvt_pk_bf16(st[qt][kt][2 * hh], st[qt][kt][2 * hh + 1]);
          *(u32a*)&pw[l15 * PSTR + kt * 16 + l4 * 4 + 2 * hh] = pk;
        }
      }
      // hard fence: P writes must complete before P fragment reads (rule 18 pattern)
      asm volatile("s_waitcnt lgkmcnt(0)" ::: "memory");
      __builtin_amdgcn_sched_barrier(0);
      // P B-fragments: lane l15 = q-row, k = kv
      bf16x8 bp0 = *(const bf16x8a*)&pw[l15 * PSTR + l4 * 8];
      bf16x8 bp1 = *(const bf16x8a*)&pw[l15 * PSTR + 32 + l4 * 8];
#pragma unroll
      for (int dt = 0; dt < 4; dt++) {
        o[qt][dt] = __builtin_amdgcn_mfma_f32_16x16x32_bf16(av[dt][0], bp0, o[qt][dt], 0, 0, 0);
        o[qt][dt] = __builtin_amdgcn_mfma_f32_16x16x32_bf16(av[dt][1], bp1, o[qt][dt], 0, 0, 0);
      }
      // P reads of this qt must finish before next qt overwrites pw
      asm volatile("s_waitcnt lgkmcnt(0)" ::: "memory");
      __builtin_amdgcn_sched_barrier(0);
    }
  }
  // epilogue: O^T lane holds q=l15, d = dt*16 + l4*4 + {0..3}
#pragma unroll
  for (int qt = 0; qt < 2; qt++) {
    float inv = 1.f / lsum[qt];
    u16* orow = O + (size_t)(bRow + q0 + qt * 16 + l15) * HID + hOff;
#pragma unroll
    for (int dt = 0; dt < 4; dt++) {
      uint2 w;
      w.x = cvt_pk_bf16(o[qt][dt][0] * inv, o[qt][dt][1] * inv);
      w.y = cvt_pk_bf16(o[qt][dt][2] * inv, o[qt][dt][3] * inv);
      *(uint2*)(orow + dt * 16 + l4 * 4) = w;
    }
  }
}

// ---------- launch ----------
extern "C" void kernel_launch(void* const* d_in, const int* in_sizes, int n_in,
                              void* d_out, int out_size, void* d_ws, size_t ws_size,
                              hipStream_t stream) {
  const float* x      = (const float*)d_in[0];
  const float* c      = (const float*)d_in[1];
  const float* W_qkv  = (const float*)d_in[2];
  const float* b_qkv  = (const float*)d_in[3];
  const float* W_proj = (const float*)d_in[4];
  const float* b_proj = (const float*)d_in[5];
  const float* W_fc1  = (const float*)d_in[6];
  const float* b_fc1  = (const float*)d_in[7];
  const float* W_fc2  = (const float*)d_in[8];
  const float* b_fc2  = (const float*)d_in[9];
  const float* W_ada  = (const float*)d_in[10];
  const float* b_ada  = (const float*)d_in[11];
  float* out = (float*)d_out;
  char* ws = (char*)d_ws;

  // workspace layout (bytes)
  float* ada  = (float*)(ws + 0);            // 8x6144 f32
  u16* WtQKV  = (u16*)(ws + 196608);         // 3072x1024 bf16
  u16* WtP    = (u16*)(ws + 6488064);        // 1024x1024 bf16
  u16* WtF1   = (u16*)(ws + 8585216);        // 4096x1024 bf16
  u16* WtF2   = (u16*)(ws + 16973824);       // 1024x4096 bf16
  u16* hbuf   = (u16*)(ws + 25362432);       // 8192x1024 bf16 (h / attnO / h2)
  u16* big    = (u16*)(ws + 42139648);       // 8192x4096 bf16 max (qkv / gelu-out)
  // ada split-K partials live inside `big` (only used before qkv GEMM writes it)
  float* apart = (float*)(ws + 42139648);    // 32x8x6144 f32 = 6.29 MB

  transpose_bf16<<<dim3(3072 / 32, 1024 / 32), 256, 0, stream>>>(W_qkv, WtQKV, 1024, 3072);
  transpose_bf16<<<dim3(1024 / 32, 1024 / 32), 256, 0, stream>>>(W_proj, WtP, 1024, 1024);
  transpose_bf16<<<dim3(4096 / 32, 1024 / 32), 256, 0, stream>>>(W_fc1, WtF1, 1024, 4096);
  transpose_bf16<<<dim3(1024 / 32, 4096 / 32), 256, 0, stream>>>(W_fc2, WtF2, 4096, 1024);
  ada_part<<<dim3(ADA_N / 256, KCH), 256, 0, stream>>>(c, W_ada, apart);
  ada_reduce<<<(BATCH * ADA_N) / 256, 256, 0, stream>>>(apart, b_ada, ada);
  ln_mod<<<8192, 256, 0, stream>>>(x, ada, 0, 1024, hbuf);
  // qkv: BN=128 -> 32*24 = 768 blocks (3 full CU rounds)
  gemm8<0, 128><<<768, 512, 0, stream>>>(hbuf, WtQKV, b_qkv, big, nullptr, nullptr, 3072, 1024);
  attn_kernel<<<1024, 256, 0, stream>>>(big, hbuf);
  // proj: BN=128 -> 256 blocks (1 round)
  gemm8<2, 128><<<256, 512, 0, stream>>>(hbuf, WtP, b_proj, out, x, ada + 2048, 1024, 1024);
  ln_mod<<<8192, 256, 0, stream>>>(out, ada, 3072, 4096, hbuf);
  // fc1: BN=256 -> 32*16 = 512 blocks (2 rounds)
  gemm8<1, 256><<<512, 512, 0, stream>>>(hbuf, WtF1, b_fc1, big, nullptr, nullptr, 4096, 1024);
  // fc2: BN=128, K=4096 -> 256 blocks (1 round)
  gemm8<2, 128><<<256, 512, 0, stream>>>(big, WtF2, b_fc2, out, out, ada + 5120, 1024, 4096);
}

// Round 14
// 397.113 us; speedup vs baseline: 1.2919x; 1.0206x over previous
//
#include <hip/hip_runtime.h>
#include <stdint.h>

typedef unsigned short u16;
typedef __attribute__((ext_vector_type(4))) float f32x4;
typedef __attribute__((ext_vector_type(8))) short bf16x8;
typedef bf16x8 bf16x8a __attribute__((may_alias));
typedef uint32_t u32a __attribute__((may_alias));

#define HID 1024
#define MLPD 4096
#define TEMB 1024
#define ADA_N 6144
#define SEQ 1024
#define BATCH 8
#define KCH 32          // ada split-K chunks
#define KCHLEN (TEMB / KCH)

// ---------- helpers ----------
__device__ __forceinline__ u16 f2bf_bits(float f) {
  uint32_t u = __float_as_uint(f);
  uint32_t r = (u + 0x7FFFu + ((u >> 16) & 1u)) >> 16;
  return (u16)r;
}

__device__ __forceinline__ uint32_t cvt_pk_bf16(float lo, float hi) {
  uint32_t r;
  asm("v_cvt_pk_bf16_f32 %0, %1, %2" : "=v"(r) : "v"(lo), "v"(hi));
  return r;
}

__device__ __forceinline__ float exp2_hw(float x) {
#if __has_builtin(__builtin_amdgcn_exp2f)
  return __builtin_amdgcn_exp2f(x);
#else
  return exp2f(x);
#endif
}

__device__ __forceinline__ void async_copy16(void* lds_dst, const void* g_src) {
  __builtin_amdgcn_global_load_lds(
      (const __attribute__((address_space(1))) void*)(uintptr_t)g_src,
      (__attribute__((address_space(3))) void*)(uint32_t)(uintptr_t)lds_dst,
      16, 0, 0);
}

__device__ __forceinline__ float gelu_tanh(float v) {
  float u = 0.7978845608028654f * (v + 0.044715f * v * v * v);
  float e = __expf(2.f * u);
  return v * e / (e + 1.f);   // = 0.5*v*(1+tanh(u))
}

// ---------- weight transpose fp32(KxN) -> bf16(NxK) ----------
__global__ __launch_bounds__(256) void transpose_bf16(const float* __restrict__ W,
                                                      u16* __restrict__ Wt, int K, int N) {
  __shared__ float tile[32][33];
  int n0 = blockIdx.x * 32, k0 = blockIdx.y * 32;
  int tx = threadIdx.x & 31, ty = threadIdx.x >> 5;   // 32 x 8
#pragma unroll
  for (int i = 0; i < 4; i++)
    tile[ty + i * 8][tx] = W[(size_t)(k0 + ty + i * 8) * N + n0 + tx];
  __syncthreads();
#pragma unroll
  for (int i = 0; i < 4; i++)
    Wt[(size_t)(n0 + ty + i * 8) * K + k0 + tx] = f2bf_bits(tile[tx][ty + i * 8]);
}

// ---------- ada split-K ----------
__global__ __launch_bounds__(256) void ada_part(const float* __restrict__ c,
                                                const float* __restrict__ W,
                                                float* __restrict__ part) {
  __shared__ float sc[BATCH * KCHLEN];
  int t = threadIdx.x;
  int col = blockIdx.x * 256 + t;
  int kc = blockIdx.y;
  int k0 = kc * KCHLEN;
  for (int i = t; i < BATCH * KCHLEN; i += 256) {
    int b = i >> 5, kk = i & (KCHLEN - 1);
    float v = c[b * TEMB + k0 + kk];
    sc[i] = v / (1.f + __expf(-v));
  }
  __syncthreads();
  float acc[BATCH] = {};
  for (int kk = 0; kk < KCHLEN; kk++) {
    float w = W[(size_t)(k0 + kk) * ADA_N + col];
#pragma unroll
    for (int b = 0; b < BATCH; b++) acc[b] += sc[b * KCHLEN + kk] * w;
  }
#pragma unroll
  for (int b = 0; b < BATCH; b++)
    part[((size_t)kc * BATCH + b) * ADA_N + col] = acc[b];
}

__global__ __launch_bounds__(256) void ada_reduce(const float* __restrict__ part,
                                                  const float* __restrict__ bias,
                                                  float* __restrict__ out) {
  int i = blockIdx.x * 256 + threadIdx.x;   // over 8*6144
  int col = i % ADA_N, b = i / ADA_N;
  float s = bias[col];
#pragma unroll
  for (int kc = 0; kc < KCH; kc++)
    s += part[((size_t)kc * BATCH + b) * ADA_N + col];
  out[(size_t)b * ADA_N + col] = s;
}

// ---------- fused LayerNorm + modulate -> bf16 ----------
__global__ __launch_bounds__(256) void ln_mod(const float* __restrict__ x,
                                              const float* __restrict__ ada,
                                              int shift_off, int scale_off,
                                              u16* __restrict__ h) {
  int row = blockIdx.x;        // 0..8191
  int bb = row >> 10;
  int t = threadIdx.x;
  const float4 v = ((const float4*)(x + (size_t)row * HID))[t];
  float s = v.x + v.y + v.z + v.w;
  float sq = v.x * v.x + v.y * v.y + v.z * v.z + v.w * v.w;
#pragma unroll
  for (int off = 32; off >= 1; off >>= 1) {
    s += __shfl_xor(s, off);
    sq += __shfl_xor(sq, off);
  }
  __shared__ float red[8];
  int wid = t >> 6;
  if ((t & 63) == 0) { red[wid] = s; red[4 + wid] = sq; }
  __syncthreads();
  s = red[0] + red[1] + red[2] + red[3];
  sq = red[4] + red[5] + red[6] + red[7];
  float mu = s * (1.0f / HID);
  float rs = rsqrtf(sq * (1.0f / HID) - mu * mu + 1e-6f);
  const float4 sc = ((const float4*)(ada + (size_t)bb * ADA_N + scale_off))[t];
  const float4 sh = ((const float4*)(ada + (size_t)bb * ADA_N + shift_off))[t];
  ushort4 o;
  o.x = f2bf_bits((v.x - mu) * rs * (1.f + sc.x) + sh.x);
  o.y = f2bf_bits((v.y - mu) * rs * (1.f + sc.y) + sh.y);
  o.z = f2bf_bits((v.z - mu) * rs * (1.f + sc.z) + sh.z);
  o.w = f2bf_bits((v.w - mu) * rs * (1.f + sc.w) + sh.w);
  ((ushort4*)(h + (size_t)row * HID))[t] = o;
}

// ---------- 8-phase 256xBN bf16 GEMM (round-6 config: session-best 404.8 us) ----------
// C(M x N) = A(M x K) * Bt(N x K)^T + bias. 512 thr / 8 waves (2M x 4N), BK=64.
// LDS tiles [rows][64] u16; chunk swizzle c16 ^= row&7 on BOTH the
// global_load_lds source and the ds_read (rule 21).
// EPI: 0 = bf16 out, 1 = gelu -> bf16 out, 2 = f32 out = resid + gate*(acc+bias)

template <int NLOAD>
__device__ __forceinline__ void stage_tile(u16* dst, const u16* gsrc, int K, int koff, int t) {
#pragma unroll
  for (int i = 0; i < NLOAD; ++i) {
    int slot = i * 512 + t;
    int row = slot >> 3, cp = slot & 7;
    const u16* src = gsrc + (size_t)row * K + koff + ((cp ^ (row & 7)) << 3);
    async_copy16(dst + slot * 8, src);
  }
}

#define LDSRD(buf, row, kk) \
  (*(const bf16x8a*)&(buf)[(row) * 64 + ((((kk) * 4 + l4) ^ ((row) & 7)) << 3)])

template <int EPI, int BN>
__global__ __launch_bounds__(512, 2) void gemm8(const u16* __restrict__ A,
                                                const u16* __restrict__ Bt,
                                                const float* __restrict__ bias,
                                                void* __restrict__ Cout,
                                                const float* __restrict__ resid,
                                                const float* __restrict__ gate,
                                                int N, int K) {
  constexpr int NR = BN / 64;       // 16x16 fragments per wave in N (4 or 2)
  constexpr int BLOADS = BN / 64;   // B stage loads per thread (4 or 2)
  constexpr int TOT = 4 + BLOADS;   // loads per thread per K-tile
  __shared__ u16 As[2][256 * 64];
  __shared__ u16 Bs[2][BN * 64];

  int t = threadIdx.x;
  int lane = t & 63, wid = t >> 6;
  int l15 = lane & 15, l4 = lane >> 4;
  int wr = wid >> 2, wc = wid & 3;            // 2 x 4 waves
  // XCD m-banding: 4 m-tiles per XCD (A-band <= 2 MB, L2-resident)
  int lid = blockIdx.x;
  int xcd = lid & 7, win = lid >> 3;
  int m0 = (xcd * 4 + (win & 3)) * 256;
  int n0 = (win >> 2) * BN;

  const u16* Abase = A + (size_t)m0 * K;
  const u16* Bbase = Bt + (size_t)n0 * K;
  f32x4 acc[8][NR] = {};

  u16 *cA = As[0], *cB = Bs[0], *nA = As[1], *nB = Bs[1];
  int nt = K / 64;
  // prologue: stage tiles 0 and 1; wait tile 0 (tile 1 stays in flight)
  stage_tile<4>(cA, Abase, K, 0, t);
  stage_tile<BLOADS>(cB, Bbase, K, 0, t);
  stage_tile<4>(nA, Abase, K, 64, t);
  stage_tile<BLOADS>(nB, Bbase, K, 64, t);
  if constexpr (TOT == 8) asm volatile("s_waitcnt vmcnt(8)" ::: "memory");
  else                    asm volatile("s_waitcnt vmcnt(6)" ::: "memory");
  __builtin_amdgcn_s_barrier();
  __builtin_amdgcn_sched_barrier(0);

  for (int ts = 0; ts < nt; ++ts) {
    bf16x8 bf[NR][2];
#pragma unroll
    for (int p = 0; p < 4; ++p) {
      if (p == 0) {
#pragma unroll
        for (int ni = 0; ni < NR; ++ni)
#pragma unroll
          for (int kk = 0; kk < 2; ++kk)
            bf[ni][kk] = LDSRD(cB, wc * (16 * NR) + ni * 16 + l15, kk);
      }
      bf16x8 af[2][2];
#pragma unroll
      for (int i = 0; i < 2; ++i)
#pragma unroll
        for (int kk = 0; kk < 2; ++kk)
          af[i][kk] = LDSRD(cA, wr * 128 + (p * 2 + i) * 16 + l15, kk);
      asm volatile("s_waitcnt lgkmcnt(0)" ::: "memory");
      __builtin_amdgcn_sched_barrier(0);
      __builtin_amdgcn_s_setprio(1);
#pragma unroll
      for (int i = 0; i < 2; ++i)
#pragma unroll
        for (int ni = 0; ni < NR; ++ni) {
          acc[p * 2 + i][ni] = __builtin_amdgcn_mfma_f32_16x16x32_bf16(af[i][0], bf[ni][0], acc[p * 2 + i][ni], 0, 0, 0);
          acc[p * 2 + i][ni] = __builtin_amdgcn_mfma_f32_16x16x32_bf16(af[i][1], bf[ni][1], acc[p * 2 + i][ni], 0, 0, 0);
        }
      __builtin_amdgcn_s_setprio(0);
      __builtin_amdgcn_sched_barrier(0);
      __builtin_amdgcn_s_barrier();   // phase boundary: all waves done reading this quadrant
      __builtin_amdgcn_sched_barrier(0);
    }
    // iteration end: cur fully read by all waves (phase-3 barrier passed).
    if (ts + 2 < nt) {
      stage_tile<4>(cA, Abase, K, (ts + 2) * 64, t);        // overwrite cur with tile t+2
      stage_tile<BLOADS>(cB, Bbase, K, (ts + 2) * 64, t);
      if constexpr (TOT == 8) asm volatile("s_waitcnt vmcnt(8)" ::: "memory");
      else                    asm volatile("s_waitcnt vmcnt(6)" ::: "memory");
    } else if (ts + 1 < nt) {
      asm volatile("s_waitcnt vmcnt(0)" ::: "memory");
    }
    __builtin_amdgcn_s_barrier();
    __builtin_amdgcn_sched_barrier(0);
    u16* tp;
    tp = cA; cA = nA; nA = tp;
    tp = cB; cB = nB; nB = tp;
  }

  int brow = m0 + wr * 128, bcol = n0 + wc * (16 * NR);
  int bb = m0 >> 10;  // 256-row tile lies within one batch
#pragma unroll
  for (int ni = 0; ni < NR; ++ni) {
    int col = bcol + ni * 16 + l15;
    float bv = bias[col];
    float gv = (EPI == 2) ? gate[(size_t)bb * ADA_N + col] : 0.f;
#pragma unroll
    for (int mi = 0; mi < 8; ++mi) {
#pragma unroll
      for (int r = 0; r < 4; ++r) {
        int row = brow + mi * 16 + l4 * 4 + r;
        float v = acc[mi][ni][r] + bv;
        if (EPI == 0) {
          ((u16*)Cout)[(size_t)row * N + col] = f2bf_bits(v);
        } else if (EPI == 1) {
          ((u16*)Cout)[(size_t)row * N + col] = f2bf_bits(gelu_tanh(v));
        } else {
          ((float*)Cout)[(size_t)row * N + col] =
              resid[(size_t)row * N + col] + gv * v;
        }
      }
    }
  }
}

// ---------- flash attention, swapped-operand structure ----------
// (256,3): 3 blocks/CU -> sliding ~12-bh KV window (~3 MB) fits the 4 MB
// per-XCD L2. (256,4) thrashes it (r12: 445 MB fetch). Do not raise occupancy.
// P scratch is DOUBLE-BUFFERED per qt -> no hard fences in the qt loop; the
// compiler's own counted lgkmcnt + in-order per-wave LDS pipe order the
// P-write -> P-read pair, and PV MFMAs may overlap the other qt's softmax.
__global__ __launch_bounds__(256, 3) void attn_kernel(const u16* __restrict__ qkv,
                                                      u16* __restrict__ O) {
  const int KSTR = 72, VSTR = 72, PSTR = 72;  // u16 strides, 16B-aligned rows
  __shared__ u16 Ks[64 * 72];       // K chunk rows [kv][d]
  __shared__ u16 Vt[64 * 72];       // V chunk transposed [d][kv]
  __shared__ u16 Plds[8 * 16 * 72]; // per-wave x per-qt P rows [q][kv]
  int t = threadIdx.x, lane = t & 63, wid = t >> 6;
  int l15 = lane & 15, l4 = lane >> 4;
  // T1: all 8 q-tiles of one (b,h) + 16 consecutive bh land on one XCD (KV L2 reuse)
  int work = ((blockIdx.x & 7) << 7) + (blockIdx.x >> 3);   // nwg = 1024
  int bh = work >> 3, qt8 = work & 7;
  int b = bh >> 4, h = bh & 15;
  int bRow = b * SEQ;
  int hOff = h * 64;
  int q0 = qt8 * 128 + wid * 32;

  // Q fragments (B-operand): lane l15 = q-row, k = d = l4*8+e
  bf16x8 qr[2][2];
#pragma unroll
  for (int qt = 0; qt < 2; qt++) {
    const u16* qbase = qkv + (size_t)(bRow + q0 + qt * 16 + l15) * 3072 + hOff;
    qr[qt][0] = *(const bf16x8a*)(qbase + l4 * 8);
    qr[qt][1] = *(const bf16x8a*)(qbase + 32 + l4 * 8);
  }

  const float csc = 0.125f * 1.4426950408889634f;  // scale * log2(e)
  float mrow[2] = {-1e30f, -1e30f};
  float lsum[2] = {0.f, 0.f};
  f32x4 o[2][4] = {};   // O^T: [qt][dt], lane: q=l15 (col), d=dt*16+l4*4+r (row)
  u16* pw0 = Plds + wid * 32 * PSTR;   // 2 x 16-row buffers per wave

  for (int cc = 0; cc < 16; cc++) {
    int kv0 = cc * 64;
    __syncthreads();
    // stage K rows (row-major, padded)
#pragma unroll
    for (int i = 0; i < 2; i++) {
      int idx = i * 256 + t;
      int row = idx >> 3, ch = idx & 7;
      bf16x8 kk = *(const bf16x8a*)(qkv + (size_t)(bRow + kv0 + row) * 3072 + 1024 + hOff + ch * 8);
      *(bf16x8a*)&Ks[row * KSTR + ch * 8] = kk;
    }
    // stage V transposed (dc-staggered scalar writes)
#pragma unroll
    for (int i = 0; i < 2; i++) {
      int idx = i * 256 + t;
      int kv = idx >> 3, dc = idx & 7;
      bf16x8 vv = *(const bf16x8a*)(qkv + (size_t)(bRow + kv0 + kv) * 3072 + 2048 + hOff + dc * 8);
#pragma unroll
      for (int j = 0; j < 8; j++) {
        int jj = (j + dc) & 7;
        Vt[(dc * 8 + jj) * VSTR + kv] = ((const u16*)&vv)[jj];
      }
    }
    __syncthreads();

    // K A-fragments: lane l15 = kv-row, k = d
    bf16x8 ak[4][2];
#pragma unroll
    for (int kt = 0; kt < 4; kt++) {
      ak[kt][0] = *(const bf16x8a*)&Ks[(kt * 16 + l15) * KSTR + l4 * 8];
      ak[kt][1] = *(const bf16x8a*)&Ks[(kt * 16 + l15) * KSTR + 32 + l4 * 8];
    }
    // S^T = K . Q^T (raw, unscaled)
    f32x4 st[2][4];
#pragma unroll
    for (int qt = 0; qt < 2; qt++)
#pragma unroll
      for (int kt = 0; kt < 4; kt++) {
        f32x4 z = {0.f, 0.f, 0.f, 0.f};
        z = __builtin_amdgcn_mfma_f32_16x16x32_bf16(ak[kt][0], qr[qt][0], z, 0, 0, 0);
        z = __builtin_amdgcn_mfma_f32_16x16x32_bf16(ak[kt][1], qr[qt][1], z, 0, 0, 0);
        st[qt][kt] = z;
      }
    // V^T A-fragments: lane l15 = d-row, k = kv
    bf16x8 av[4][2];
#pragma unroll
    for (int dt = 0; dt < 4; dt++) {
      av[dt][0] = *(const bf16x8a*)&Vt[(dt * 16 + l15) * VSTR + l4 * 8];
      av[dt][1] = *(const bf16x8a*)&Vt[(dt * 16 + l15) * VSTR + 32 + l4 * 8];
    }

#pragma unroll
    for (int qt = 0; qt < 2; qt++) {
      u16* pwq = pw0 + qt * 16 * PSTR;
      float mx = st[qt][0][0];
#pragma unroll
      for (int kt = 0; kt < 4; kt++)
#pragma unroll
        for (int r = 0; r < 4; r++) mx = fmaxf(mx, st[qt][kt][r]);
      mx = fmaxf(mx, __shfl_xor(mx, 16));
      mx = fmaxf(mx, __shfl_xor(mx, 32));
      float mn = fmaxf(mrow[qt], mx * csc);
      float al = exp2_hw(mrow[qt] - mn);
      mrow[qt] = mn;
      float rs = 0.f;
#pragma unroll
      for (int kt = 0; kt < 4; kt++)
#pragma unroll
        for (int r = 0; r < 4; r++) {
          float p = exp2_hw(__builtin_fmaf(st[qt][kt][r], csc, -mn));
          st[qt][kt][r] = p;
          rs += p;
        }
      rs += __shfl_xor(rs, 16);
      rs += __shfl_xor(rs, 32);
      lsum[qt] = lsum[qt] * al + rs;
#pragma unroll
      for (int dt = 0; dt < 4; dt++) o[qt][dt] *= al;
      // P -> LDS row q=l15 via packed bf16 writes (may_alias keeps the
      // write->read pair ordered; per-qt buffer removes the overwrite hazard)
#pragma unroll
      for (int kt = 0; kt < 4; kt++) {
#pragma unroll
        for (int hh = 0; hh < 2; hh++) {
          uint32_t pk = cvt_pk_bf16(st[qt][kt][2 * hh], st[qt][kt][2 * hh + 1]);
          *(u32a*)&pwq[l15 * PSTR + kt * 16 + l4 * 4 + 2 * hh] = pk;
        }
      }
      // P B-fragments: lane l15 = q-row, k = kv
      bf16x8 bp0 = *(const bf16x8a*)&pwq[l15 * PSTR + l4 * 8];
      bf16x8 bp1 = *(const bf16x8a*)&pwq[l15 * PSTR + 32 + l4 * 8];
#pragma unroll
      for (int dt = 0; dt < 4; dt++) {
        o[qt][dt] = __builtin_amdgcn_mfma_f32_16x16x32_bf16(av[dt][0], bp0, o[qt][dt], 0, 0, 0);
        o[qt][dt] = __builtin_amdgcn_mfma_f32_16x16x32_bf16(av[dt][1], bp1, o[qt][dt], 0, 0, 0);
      }
    }
  }
  // epilogue: O^T lane holds q=l15, d = dt*16 + l4*4 + {0..3}
#pragma unroll
  for (int qt = 0; qt < 2; qt++) {
    float inv = 1.f / lsum[qt];
    u16* orow = O + (size_t)(bRow + q0 + qt * 16 + l15) * HID + hOff;
#pragma unroll
    for (int dt = 0; dt < 4; dt++) {
      uint2 w;
      w.x = cvt_pk_bf16(o[qt][dt][0] * inv, o[qt][dt][1] * inv);
      w.y = cvt_pk_bf16(o[qt][dt][2] * inv, o[qt][dt][3] * inv);
      *(uint2*)(orow + dt * 16 + l4 * 4) = w;
    }
  }
}

// ---------- launch ----------
extern "C" void kernel_launch(void* const* d_in, const int* in_sizes, int n_in,
                              void* d_out, int out_size, void* d_ws, size_t ws_size,
                              hipStream_t stream) {
  const float* x      = (const float*)d_in[0];
  const float* c      = (const float*)d_in[1];
  const float* W_qkv  = (const float*)d_in[2];
  const float* b_qkv  = (const float*)d_in[3];
  const float* W_proj = (const float*)d_in[4];
  const float* b_proj = (const float*)d_in[5];
  const float* W_fc1  = (const float*)d_in[6];
  const float* b_fc1  = (const float*)d_in[7];
  const float* W_fc2  = (const float*)d_in[8];
  const float* b_fc2  = (const float*)d_in[9];
  const float* W_ada  = (const float*)d_in[10];
  const float* b_ada  = (const float*)d_in[11];
  float* out = (float*)d_out;
  char* ws = (char*)d_ws;

  // workspace layout (bytes)
  float* ada  = (float*)(ws + 0);            // 8x6144 f32
  u16* WtQKV  = (u16*)(ws + 196608);         // 3072x1024 bf16
  u16* WtP    = (u16*)(ws + 6488064);        // 1024x1024 bf16
  u16* WtF1   = (u16*)(ws + 8585216);        // 4096x1024 bf16
  u16* WtF2   = (u16*)(ws + 16973824);       // 1024x4096 bf16
  u16* hbuf   = (u16*)(ws + 25362432);       // 8192x1024 bf16 (h / attnO / h2)
  u16* big    = (u16*)(ws + 42139648);       // 8192x4096 bf16 max (qkv / gelu-out)
  // ada split-K partials live inside `big` (only used before qkv GEMM writes it)
  float* apart = (float*)(ws + 42139648);    // 32x8x6144 f32 = 6.29 MB

  transpose_bf16<<<dim3(3072 / 32, 1024 / 32), 256, 0, stream>>>(W_qkv, WtQKV, 1024, 3072);
  transpose_bf16<<<dim3(1024 / 32, 1024 / 32), 256, 0, stream>>>(W_proj, WtP, 1024, 1024);
  transpose_bf16<<<dim3(4096 / 32, 1024 / 32), 256, 0, stream>>>(W_fc1, WtF1, 1024, 4096);
  transpose_bf16<<<dim3(1024 / 32, 4096 / 32), 256, 0, stream>>>(W_fc2, WtF2, 4096, 1024);
  ada_part<<<dim3(ADA_N / 256, KCH), 256, 0, stream>>>(c, W_ada, apart);
  ada_reduce<<<(BATCH * ADA_N) / 256, 256, 0, stream>>>(apart, b_ada, ada);
  ln_mod<<<8192, 256, 0, stream>>>(x, ada, 0, 1024, hbuf);
  // qkv: BN=128 -> 32*24 = 768 blocks (3 full CU rounds)
  gemm8<0, 128><<<768, 512, 0, stream>>>(hbuf, WtQKV, b_qkv, big, nullptr, nullptr, 3072, 1024);
  attn_kernel<<<1024, 256, 0, stream>>>(big, hbuf);
  // proj: BN=128 -> 256 blocks (1 round)
  gemm8<2, 128><<<256, 512, 0, stream>>>(hbuf, WtP, b_proj, out, x, ada + 2048, 1024, 1024);
  ln_mod<<<8192, 256, 0, stream>>>(out, ada, 3072, 4096, hbuf);
  // fc1: BN=256 -> 32*16 = 512 blocks (2 rounds)
  gemm8<1, 256><<<512, 512, 0, stream>>>(hbuf, WtF1, b_fc1, big, nullptr, nullptr, 4096, 1024);
  // fc2: BN=128, K=4096 -> 256 blocks (1 round)
  gemm8<2, 128><<<256, 512, 0, stream>>>(big, WtF2, b_fc2, out, out, ada + 5120, 1024, 4096);
}